// Round 1
// baseline (4602.703 us; speedup 1.0000x reference)
//
#include <hip/hip_runtime.h>
#include <math.h>

#define D_MODEL 1024
#define NHEADS  16
#define DHEAD   64
#define D_HID   4096

// ---------------------------------------------------------------------------
// GEMM: C[M,N] = A[M,K] * B[N,K]^T   (+bias) (+relu) (+=accumulate)
// A row-major lda, B row-major ldb (weight layout [N][K] == nn.Linear), C ldc.
// Tile 64x64, BK=16, 256 threads, each thread 4x4 outputs.
// ---------------------------------------------------------------------------
template<bool BIAS, bool RELU, bool ACCUM>
__global__ __launch_bounds__(256) void gemm_bt(
    const float* __restrict__ A, int lda,
    const float* __restrict__ Bm, int ldb,
    const float* __restrict__ bias,
    float* __restrict__ C, int ldc,
    int M, int N, int K)
{
    const int BM = 64, BN = 64, BK = 16;
    __shared__ float As[BK][BM + 4];
    __shared__ float Bs[BK][BN + 4];

    const int bm = blockIdx.y * BM;
    const int bn = blockIdx.x * BN;
    const int tid = threadIdx.x;
    const int tx = tid & 15, ty = tid >> 4;
    const int lrow = tid >> 2;            // 0..63
    const int lkq  = (tid & 3) * 4;       // 0,4,8,12

    float acc[4][4] = {};

    for (int k0 = 0; k0 < K; k0 += BK) {
        float4 av = *(const float4*)(A  + (size_t)(bm + lrow) * lda + k0 + lkq);
        float4 bv = *(const float4*)(Bm + (size_t)(bn + lrow) * ldb + k0 + lkq);
        As[lkq + 0][lrow] = av.x; As[lkq + 1][lrow] = av.y;
        As[lkq + 2][lrow] = av.z; As[lkq + 3][lrow] = av.w;
        Bs[lkq + 0][lrow] = bv.x; Bs[lkq + 1][lrow] = bv.y;
        Bs[lkq + 2][lrow] = bv.z; Bs[lkq + 3][lrow] = bv.w;
        __syncthreads();

        #pragma unroll
        for (int kk = 0; kk < BK; ++kk) {
            float a[4], b[4];
            #pragma unroll
            for (int i = 0; i < 4; ++i) a[i] = As[kk][ty * 4 + i];
            #pragma unroll
            for (int j = 0; j < 4; ++j) b[j] = Bs[kk][tx * 4 + j];
            #pragma unroll
            for (int i = 0; i < 4; ++i)
                #pragma unroll
                for (int j = 0; j < 4; ++j)
                    acc[i][j] += a[i] * b[j];
        }
        __syncthreads();
    }

    #pragma unroll
    for (int i = 0; i < 4; ++i) {
        size_t off = (size_t)(bm + ty * 4 + i) * ldc + bn + tx * 4;
        float4 v = make_float4(acc[i][0], acc[i][1], acc[i][2], acc[i][3]);
        if (ACCUM) {
            float4 c = *(const float4*)(C + off);
            v.x += c.x; v.y += c.y; v.z += c.z; v.w += c.w;
        }
        if (BIAS) {
            float4 bb = *(const float4*)(bias + bn + tx * 4);
            v.x += bb.x; v.y += bb.y; v.z += bb.z; v.w += bb.w;
        }
        if (RELU) {
            v.x = fmaxf(v.x, 0.f); v.y = fmaxf(v.y, 0.f);
            v.z = fmaxf(v.z, 0.f); v.w = fmaxf(v.w, 0.f);
        }
        *(float4*)(C + off) = v;
    }
}

// ---------------------------------------------------------------------------
// Flash-style attention, fp32. Q,K,V,O: [B,S,D_MODEL], head h = cols h*64..h*64+63.
// scores = Q.K^T ; if causal: scores -= 1e10 above diag (BEFORE scaling);
// att = softmax(scores / sqrt(D_MODEL)=32). O = att.V
// Block: 256 threads, QB=32 q-rows, KB=32 k-rows per tile.
// Thread t: q-row r=t>>3, dim group g=t&7 (owns 8 output dims), also computes
// S-tile entries (row r, cols g*4..g*4+3).
// ---------------------------------------------------------------------------
template<bool CAUSAL>
__global__ __launch_bounds__(256) void attn_kernel(
    const float* __restrict__ Q, const float* __restrict__ K,
    const float* __restrict__ V, float* __restrict__ O, int S)
{
    const int QB = 32, KB = 32;
    __shared__ float Qs[QB][DHEAD + 1];
    __shared__ float Ks[KB][DHEAD + 1];
    __shared__ float Vs[KB][DHEAD + 1];
    __shared__ float Ps[QB][KB + 1];

    const int tid = threadIdx.x;
    const int qb  = blockIdx.x * QB;
    const int h   = blockIdx.y;
    const int b   = blockIdx.z;
    const size_t base = ((size_t)b * S) * D_MODEL + (size_t)h * DHEAD;

    // stage Q tile
    for (int t = tid; t < QB * DHEAD / 4; t += 256) {
        int i = t >> 4, d4 = (t & 15) * 4;
        float4 qv = *(const float4*)(Q + base + (size_t)(qb + i) * D_MODEL + d4);
        Qs[i][d4 + 0] = qv.x; Qs[i][d4 + 1] = qv.y;
        Qs[i][d4 + 2] = qv.z; Qs[i][d4 + 3] = qv.w;
    }

    const int r = tid >> 3;     // q row within tile
    const int g = tid & 7;      // dim group (8 dims)
    float o[8] = {0, 0, 0, 0, 0, 0, 0, 0};
    float m = -3.0e38f, l = 0.f;

    const int nkt = CAUSAL ? (qb / KB + 1) : (S / KB);
    const int qi = qb + r;

    for (int kt = 0; kt < nkt; ++kt) {
        const int k0 = kt * KB;
        __syncthreads();   // previous tile's Ps/Vs reads done before overwrite
        for (int t = tid; t < KB * DHEAD / 4; t += 256) {
            int i = t >> 4, d4 = (t & 15) * 4;
            float4 kv = *(const float4*)(K + base + (size_t)(k0 + i) * D_MODEL + d4);
            Ks[i][d4 + 0] = kv.x; Ks[i][d4 + 1] = kv.y;
            Ks[i][d4 + 2] = kv.z; Ks[i][d4 + 3] = kv.w;
            float4 vv = *(const float4*)(V + base + (size_t)(k0 + i) * D_MODEL + d4);
            Vs[i][d4 + 0] = vv.x; Vs[i][d4 + 1] = vv.y;
            Vs[i][d4 + 2] = vv.z; Vs[i][d4 + 3] = vv.w;
        }
        __syncthreads();

        // S tile: row r, cols g*4 .. g*4+3
        const int j4 = g * 4;
        float s0 = 0.f, s1 = 0.f, s2 = 0.f, s3 = 0.f;
        #pragma unroll
        for (int d = 0; d < DHEAD; ++d) {
            float qd = Qs[r][d];
            s0 += qd * Ks[j4 + 0][d];
            s1 += qd * Ks[j4 + 1][d];
            s2 += qd * Ks[j4 + 2][d];
            s3 += qd * Ks[j4 + 3][d];
        }
        float sv[4] = {s0, s1, s2, s3};
        #pragma unroll
        for (int jj = 0; jj < 4; ++jj) {
            if (CAUSAL && (k0 + j4 + jj) > qi) sv[jj] -= 1.0e10f;  // mask BEFORE scale
            sv[jj] *= 0.03125f;                                     // / sqrt(1024)
            Ps[r][j4 + jj] = sv[jj];
        }
        __syncthreads();

        // online softmax for row r (8 threads of the row do this redundantly)
        float tmax = -3.0e38f;
        #pragma unroll
        for (int j = 0; j < KB; ++j) tmax = fmaxf(tmax, Ps[r][j]);
        float mnew = fmaxf(m, tmax);
        float sc = __expf(m - mnew);
        l *= sc;
        #pragma unroll
        for (int dd = 0; dd < 8; ++dd) o[dd] *= sc;
        for (int j = 0; j < KB; ++j) {
            float p = __expf(Ps[r][j] - mnew);
            l += p;
            const float* vrow = &Vs[j][g * 8];
            #pragma unroll
            for (int dd = 0; dd < 8; ++dd) o[dd] += p * vrow[dd];
        }
        m = mnew;
    }

    const float invl = 1.f / l;
    size_t orow = base + (size_t)(qb + r) * D_MODEL + g * 8;
    float4 v0 = make_float4(o[0] * invl, o[1] * invl, o[2] * invl, o[3] * invl);
    float4 v1 = make_float4(o[4] * invl, o[5] * invl, o[6] * invl, o[7] * invl);
    *(float4*)(O + orow)     = v0;
    *(float4*)(O + orow + 4) = v1;
}

// ---------------------------------------------------------------------------
// y = LayerNorm(x + r) with unbiased std (N-1) and /(std + eps), per reference.
// One block per row of 1024. 256 threads x 4 elements.
// ---------------------------------------------------------------------------
__global__ __launch_bounds__(256) void add_ln(
    const float* __restrict__ x, const float* __restrict__ rr,
    const float* __restrict__ gam, const float* __restrict__ bet,
    float* __restrict__ y)
{
    const int row = blockIdx.x;
    const int tid = threadIdx.x;
    const size_t off = (size_t)row * D_MODEL;

    float4 xv = ((const float4*)(x + off))[tid];
    float4 rv = ((const float4*)(rr + off))[tid];
    float v0 = xv.x + rv.x, v1 = xv.y + rv.y, v2 = xv.z + rv.z, v3 = xv.w + rv.w;

    float s  = v0 + v1 + v2 + v3;
    float ss = v0 * v0 + v1 * v1 + v2 * v2 + v3 * v3;

    __shared__ float sb[8];
    #pragma unroll
    for (int o = 32; o > 0; o >>= 1) {
        s  += __shfl_down(s, o, 64);
        ss += __shfl_down(ss, o, 64);
    }
    const int lane = tid & 63, w = tid >> 6;
    if (lane == 0) { sb[w] = s; sb[4 + w] = ss; }
    __syncthreads();
    float S  = sb[0] + sb[1] + sb[2] + sb[3];
    float SS = sb[4] + sb[5] + sb[6] + sb[7];

    float mean = S * (1.f / D_MODEL);
    float var_sum = SS - S * mean;                 // sum((v-mean)^2)
    float stdv = sqrtf(var_sum * (1.f / (D_MODEL - 1)));
    float inv = 1.f / (stdv + 1e-6f);

    float4 gv = ((const float4*)gam)[tid];
    float4 bv = ((const float4*)bet)[tid];
    float4 out;
    out.x = gv.x * (v0 - mean) * inv + bv.x;
    out.y = gv.y * (v1 - mean) * inv + bv.y;
    out.z = gv.z * (v2 - mean) * inv + bv.z;
    out.w = gv.w * (v3 - mean) * inv + bv.w;
    ((float4*)(y + off))[tid] = out;
}

// ---------------------------------------------------------------------------
extern "C" void kernel_launch(void* const* d_in, const int* in_sizes, int n_in,
                              void* d_out, int out_size, void* d_ws, size_t ws_size,
                              hipStream_t stream)
{
    const float* x     = (const float*)d_in[0];
    const float* enc   = (const float*)d_in[1];
    const float* sa_wq = (const float*)d_in[2];
    const float* sa_wk = (const float*)d_in[3];
    const float* sa_wv = (const float*)d_in[4];
    const float* sa_wo = (const float*)d_in[5];
    const float* ca_wq = (const float*)d_in[6];
    const float* ca_wk = (const float*)d_in[7];
    const float* ca_wv = (const float*)d_in[8];
    const float* ca_wo = (const float*)d_in[9];
    const float* ff_w1 = (const float*)d_in[10];
    const float* ff_b1 = (const float*)d_in[11];
    const float* ff_w2 = (const float*)d_in[12];
    const float* ff_b2 = (const float*)d_in[13];
    const float* ln1_g = (const float*)d_in[14];
    const float* ln1_b = (const float*)d_in[15];
    const float* ln2_g = (const float*)d_in[16];
    const float* ln2_b = (const float*)d_in[17];
    const float* ln3_g = (const float*)d_in[18];
    const float* ln3_b = (const float*)d_in[19];
    float* out = (float*)d_out;

    const int Bn = 2, S = 2048, M = Bn * S;        // M = 4096 rows
    const size_t SLOT = (size_t)M * D_MODEL;       // 16 MB each
    float* s0 = (float*)d_ws;
    float* s1 = s0 + SLOT;
    float* s2 = s1 + SLOT;
    float* s3 = s2 + SLOT;
    float* s4 = s3 + SLOT;
    // peak ws use: 5 slots = 80 MB

    dim3 blk(256);
    dim3 g_proj(D_MODEL / 64, M / 64);             // N=1024 GEMMs
    dim3 g_ffh(2048 / 64, M / 64);                 // N=2048 (FFN half)
    dim3 g_attn(S / 32, NHEADS, Bn);
    dim3 g_ln(M);

    // ---- self-attention (causal) ----
    gemm_bt<false,false,false><<<g_proj, blk, 0, stream>>>(x, D_MODEL, sa_wq, D_MODEL, nullptr, s0, D_MODEL, M, D_MODEL, D_MODEL);
    gemm_bt<false,false,false><<<g_proj, blk, 0, stream>>>(x, D_MODEL, sa_wk, D_MODEL, nullptr, s1, D_MODEL, M, D_MODEL, D_MODEL);
    gemm_bt<false,false,false><<<g_proj, blk, 0, stream>>>(x, D_MODEL, sa_wv, D_MODEL, nullptr, s2, D_MODEL, M, D_MODEL, D_MODEL);
    attn_kernel<true><<<g_attn, blk, 0, stream>>>(s0, s1, s2, s3, S);
    gemm_bt<false,false,false><<<g_proj, blk, 0, stream>>>(s3, D_MODEL, sa_wo, D_MODEL, nullptr, s4, D_MODEL, M, D_MODEL, D_MODEL);
    add_ln<<<g_ln, blk, 0, stream>>>(x, s4, ln1_g, ln1_b, s1);   // h1 -> s1

    // ---- cross-attention ----
    gemm_bt<false,false,false><<<g_proj, blk, 0, stream>>>(s1, D_MODEL, ca_wq, D_MODEL, nullptr, s0, D_MODEL, M, D_MODEL, D_MODEL);
    gemm_bt<false,false,false><<<g_proj, blk, 0, stream>>>(enc, D_MODEL, ca_wk, D_MODEL, nullptr, s2, D_MODEL, M, D_MODEL, D_MODEL);
    gemm_bt<false,false,false><<<g_proj, blk, 0, stream>>>(enc, D_MODEL, ca_wv, D_MODEL, nullptr, s3, D_MODEL, M, D_MODEL, D_MODEL);
    attn_kernel<false><<<g_attn, blk, 0, stream>>>(s0, s2, s3, s4, S);
    gemm_bt<false,false,false><<<g_proj, blk, 0, stream>>>(s4, D_MODEL, ca_wo, D_MODEL, nullptr, s0, D_MODEL, M, D_MODEL, D_MODEL);
    add_ln<<<g_ln, blk, 0, stream>>>(s1, s0, ln2_g, ln2_b, s2);  // h2 -> s2

    // ---- FFN, K-split into two halves (t_half lives in s3..s4, 2 slots) ----
    // half 1: t1 = relu(h2 @ w1[0:2048].T + b1[0:2048]) ; f = t1 @ w2[:,0:2048].T
    gemm_bt<true,true,false><<<g_ffh, blk, 0, stream>>>(s2, D_MODEL, ff_w1, D_MODEL, ff_b1, s3, 2048, M, 2048, D_MODEL);
    gemm_bt<false,false,false><<<g_proj, blk, 0, stream>>>(s3, 2048, ff_w2, D_HID, nullptr, s0, D_MODEL, M, D_MODEL, 2048);
    // half 2: t2 = relu(h2 @ w1[2048:4096].T + b1[2048:]) ; f += t2 @ w2[:,2048:].T + b2
    gemm_bt<true,true,false><<<g_ffh, blk, 0, stream>>>(s2, D_MODEL, ff_w1 + (size_t)2048 * D_MODEL, D_MODEL, ff_b1 + 2048, s3, 2048, M, 2048, D_MODEL);
    gemm_bt<true,false,true><<<g_proj, blk, 0, stream>>>(s3, 2048, ff_w2 + 2048, D_HID, ff_b2, s0, D_MODEL, M, D_MODEL, 2048);

    add_ln<<<g_ln, blk, 0, stream>>>(s2, s0, ln3_g, ln3_b, out); // final -> d_out
}

// Round 2
// 2207.014 us; speedup vs baseline: 2.0855x; 2.0855x over previous
//
#include <hip/hip_runtime.h>
#include <hip/hip_bf16.h>
#include <math.h>

#define D_MODEL 1024
#define NHEADS  16
#define DHEAD   64
#define D_HID   4096

typedef __attribute__((ext_vector_type(8))) short short8;   // 8 bf16 = 4 VGPR
typedef __attribute__((ext_vector_type(4))) float f32x4;    // mfma accumulator

__device__ inline short f2bs(float x) {
    union { __hip_bfloat16 b; short s; } u;
    u.b = __float2bfloat16(x);
    return u.s;
}
__device__ inline short8 pack8(float4 x, float4 y) {
    short8 v;
    v[0] = f2bs(x.x); v[1] = f2bs(x.y); v[2] = f2bs(x.z); v[3] = f2bs(x.w);
    v[4] = f2bs(y.x); v[5] = f2bs(y.y); v[6] = f2bs(y.z); v[7] = f2bs(y.w);
    return v;
}
// XOR swizzle (guide §6 G4): spreads a [row][128B] tile's column reads across banks.
__device__ inline int swz(int r, int byteInRow) {
    return (r * 128 + byteInRow) ^ ((r & 7) << 4);
}

// ---------------------------------------------------------------------------
// GEMM: C[M,N] = A[M,K] * B[N,K]^T  (+bias)(+relu)(+=acc). fp32, 64x64 tile.
// ---------------------------------------------------------------------------
template<bool BIAS, bool RELU, bool ACCUM>
__global__ __launch_bounds__(256) void gemm_bt(
    const float* __restrict__ A, int lda,
    const float* __restrict__ Bm, int ldb,
    const float* __restrict__ bias,
    float* __restrict__ C, int ldc,
    int M, int N, int K)
{
    const int BM = 64, BN = 64, BK = 16;
    __shared__ float As[BK][BM + 4];
    __shared__ float Bs[BK][BN + 4];

    const int bm = blockIdx.y * BM;
    const int bn = blockIdx.x * BN;
    const int tid = threadIdx.x;
    const int tx = tid & 15, ty = tid >> 4;
    const int lrow = tid >> 2;
    const int lkq  = (tid & 3) * 4;

    float acc[4][4] = {};

    for (int k0 = 0; k0 < K; k0 += BK) {
        float4 av = *(const float4*)(A  + (size_t)(bm + lrow) * lda + k0 + lkq);
        float4 bv = *(const float4*)(Bm + (size_t)(bn + lrow) * ldb + k0 + lkq);
        As[lkq + 0][lrow] = av.x; As[lkq + 1][lrow] = av.y;
        As[lkq + 2][lrow] = av.z; As[lkq + 3][lrow] = av.w;
        Bs[lkq + 0][lrow] = bv.x; Bs[lkq + 1][lrow] = bv.y;
        Bs[lkq + 2][lrow] = bv.z; Bs[lkq + 3][lrow] = bv.w;
        __syncthreads();

        #pragma unroll
        for (int kk = 0; kk < BK; ++kk) {
            float a[4], b[4];
            #pragma unroll
            for (int i = 0; i < 4; ++i) a[i] = As[kk][ty * 4 + i];
            #pragma unroll
            for (int j = 0; j < 4; ++j) b[j] = Bs[kk][tx * 4 + j];
            #pragma unroll
            for (int i = 0; i < 4; ++i)
                #pragma unroll
                for (int j = 0; j < 4; ++j)
                    acc[i][j] += a[i] * b[j];
        }
        __syncthreads();
    }

    #pragma unroll
    for (int i = 0; i < 4; ++i) {
        size_t off = (size_t)(bm + ty * 4 + i) * ldc + bn + tx * 4;
        float4 v = make_float4(acc[i][0], acc[i][1], acc[i][2], acc[i][3]);
        if (ACCUM) {
            float4 c = *(const float4*)(C + off);
            v.x += c.x; v.y += c.y; v.z += c.z; v.w += c.w;
        }
        if (BIAS) {
            float4 bb = *(const float4*)(bias + bn + tx * 4);
            v.x += bb.x; v.y += bb.y; v.z += bb.z; v.w += bb.w;
        }
        if (RELU) {
            v.x = fmaxf(v.x, 0.f); v.y = fmaxf(v.y, 0.f);
            v.z = fmaxf(v.z, 0.f); v.w = fmaxf(v.w, 0.f);
        }
        *(float4*)(C + off) = v;
    }
}

// ---------------------------------------------------------------------------
// kv_prep: per (kv-tile, head) block.
//  Kb[bh][t][r][d]  = bf16 cast of K rows (linear 64x64 tile, 8KB contiguous)
//  Vtb[bh][t][d][k] = bf16 TRANSPOSED V tile (so PV's B-operand reads rows)
// ---------------------------------------------------------------------------
__global__ __launch_bounds__(256) void kv_prep(
    const float* __restrict__ Kf, const float* __restrict__ Vf,
    short* __restrict__ Kb, short* __restrict__ Vtb, int S)
{
    const int t = blockIdx.x, bh = blockIdx.y;
    const int b = bh >> 4, h = bh & 15;
    const int tid = threadIdx.x;
    const int r = tid >> 2, g = tid & 3;
    __shared__ float vs[64][65];

    const size_t inrow = ((size_t)b * S + t * 64 + r) * D_MODEL + h * DHEAD;
    const size_t tbase = ((size_t)bh * (S / 64) + t) * 4096;

    // K: cast rows
    float4 a0 = *(const float4*)(Kf + inrow + g * 8);
    float4 a1 = *(const float4*)(Kf + inrow + g * 8 + 4);
    float4 a2 = *(const float4*)(Kf + inrow + 32 + g * 8);
    float4 a3 = *(const float4*)(Kf + inrow + 32 + g * 8 + 4);
    *(short8*)(Kb + tbase + r * 64 + g * 8)      = pack8(a0, a1);
    *(short8*)(Kb + tbase + r * 64 + 32 + g * 8) = pack8(a2, a3);

    // V: stage to LDS, transpose, cast
    float4 v0 = *(const float4*)(Vf + inrow + g * 16);
    float4 v1 = *(const float4*)(Vf + inrow + g * 16 + 4);
    float4 v2 = *(const float4*)(Vf + inrow + g * 16 + 8);
    float4 v3 = *(const float4*)(Vf + inrow + g * 16 + 12);
    vs[r][g*16+0]=v0.x;  vs[r][g*16+1]=v0.y;  vs[r][g*16+2]=v0.z;  vs[r][g*16+3]=v0.w;
    vs[r][g*16+4]=v1.x;  vs[r][g*16+5]=v1.y;  vs[r][g*16+6]=v1.z;  vs[r][g*16+7]=v1.w;
    vs[r][g*16+8]=v2.x;  vs[r][g*16+9]=v2.y;  vs[r][g*16+10]=v2.z; vs[r][g*16+11]=v2.w;
    vs[r][g*16+12]=v3.x; vs[r][g*16+13]=v3.y; vs[r][g*16+14]=v3.z; vs[r][g*16+15]=v3.w;
    __syncthreads();

    // write Vt rows: d = r, k = g*16 .. +16  (reads LDS column d=r)
    short8 q0, q1;
    #pragma unroll
    for (int j = 0; j < 8; ++j) {
        q0[j] = f2bs(vs[g * 16 + j][r]);
        q1[j] = f2bs(vs[g * 16 + 8 + j][r]);
    }
    *(short8*)(Vtb + tbase + r * 64 + g * 16)     = q0;
    *(short8*)(Vtb + tbase + r * 64 + g * 16 + 8) = q1;
}

// ---------------------------------------------------------------------------
// MFMA flash attention. Block = 64 q-rows of one (b,h); 4 waves x 16 rows.
// Q read fp32 (cast in-reg); K/Vt tiles staged bf16 into XOR-swizzled LDS.
// mask BEFORE /32 scale; online softmax per row held in (lane>>4, reg) pairs.
// ---------------------------------------------------------------------------
template<bool CAUSAL>
__global__ __launch_bounds__(256) void attn_mfma(
    const float* __restrict__ Qf, const short* __restrict__ Kb,
    const short* __restrict__ Vtb, float* __restrict__ O, int S)
{
    __shared__ __align__(16) char Ks[8192];
    __shared__ __align__(16) char Vt[8192];
    __shared__ __align__(16) char Ps[8192];

    const int tid = threadIdx.x, w = tid >> 6, l = tid & 63;
    const int l15 = l & 15, lhi = l >> 4;
    const int qt = blockIdx.x, bh = blockIdx.y;
    const int b = bh >> 4, h = bh & 15;
    const int qb = qt * 64;

    // Q fragments (A-operand): row = w*16 + l15, k(d) = kd*32 + lhi*8 .. +8
    short8 aq[2];
    {
        const size_t qrow = ((size_t)b * S + qb + w * 16 + l15) * D_MODEL + h * DHEAD;
        #pragma unroll
        for (int kd = 0; kd < 2; ++kd) {
            const float* qp = Qf + qrow + kd * 32 + lhi * 8;
            float4 f0 = *(const float4*)qp;
            float4 f1 = *(const float4*)(qp + 4);
            aq[kd] = pack8(f0, f1);
        }
    }

    f32x4 oA[4] = {};
    float m_run[4] = {-3.0e38f, -3.0e38f, -3.0e38f, -3.0e38f};
    float l_run[4] = {0.f, 0.f, 0.f, 0.f};

    const int nkt = CAUSAL ? (qt + 1) : (S / 64);
    const size_t hKbase = (size_t)bh * ((S / 64) * 4096);
    const int sr = tid >> 2, sg = tid & 3;
    const int wbase = w * 2048;     // wave-private 16x128B P region

    for (int kt = 0; kt < nkt; ++kt) {
        __syncthreads();   // prior iteration's LDS reads complete
        {
            const short* kg = Kb  + hKbase + (size_t)kt * 4096;
            const short* vg = Vtb + hKbase + (size_t)kt * 4096;
            short8 k0 = *(const short8*)(kg + sr * 64 + sg * 8);
            short8 k1 = *(const short8*)(kg + sr * 64 + 32 + sg * 8);
            short8 v0 = *(const short8*)(vg + sr * 64 + sg * 8);
            short8 v1 = *(const short8*)(vg + sr * 64 + 32 + sg * 8);
            *(short8*)(Ks + swz(sr, sg * 16))      = k0;
            *(short8*)(Ks + swz(sr, 64 + sg * 16)) = k1;
            *(short8*)(Vt + swz(sr, sg * 16))      = v0;
            *(short8*)(Vt + swz(sr, 64 + sg * 16)) = v1;
        }
        __syncthreads();   // staging visible

        // ---- QK^T: S_tile[16 q][64 k] = 4 col-chunks x 2 k(d)-chunks ----
        f32x4 sA[4] = {};
        #pragma unroll
        for (int kd = 0; kd < 2; ++kd) {
            #pragma unroll
            for (int c = 0; c < 4; ++c) {
                short8 bfr = *(const short8*)(Ks + swz(c * 16 + l15, kd * 64 + lhi * 16));
                sA[c] = __builtin_amdgcn_mfma_f32_16x16x32_bf16(aq[kd], bfr, sA[c], 0, 0, 0);
            }
        }

        // ---- mask (before scale) + scale ----
        float sv[4][4];
        #pragma unroll
        for (int c = 0; c < 4; ++c) {
            #pragma unroll
            for (int i = 0; i < 4; ++i) {
                float s = sA[c][i];
                if (CAUSAL) {
                    int col  = kt * 64 + c * 16 + l15;
                    int qrow = qb + w * 16 + lhi * 4 + i;
                    if (col > qrow) s -= 1.0e10f;
                }
                sv[c][i] = s * 0.03125f;   // 1/sqrt(1024)
            }
        }

        // ---- online softmax: rows live at (lhi, reg i), 16 lanes share a row ----
        float rmax[4];
        #pragma unroll
        for (int i = 0; i < 4; ++i)
            rmax[i] = fmaxf(fmaxf(sv[0][i], sv[1][i]), fmaxf(sv[2][i], sv[3][i]));
        #pragma unroll
        for (int d = 1; d < 16; d <<= 1)
            #pragma unroll
            for (int i = 0; i < 4; ++i)
                rmax[i] = fmaxf(rmax[i], __shfl_xor(rmax[i], d, 64));

        float corr[4], psum[4];
        #pragma unroll
        for (int i = 0; i < 4; ++i) {
            float mn = fmaxf(m_run[i], rmax[i]);
            corr[i]  = __expf(m_run[i] - mn);
            m_run[i] = mn;
            psum[i]  = 0.f;
        }
        ushort pb[4][4];
        #pragma unroll
        for (int c = 0; c < 4; ++c)
            #pragma unroll
            for (int i = 0; i < 4; ++i) {
                float p = __expf(sv[c][i] - m_run[i]);
                psum[i] += p;
                pb[c][i] = (ushort)f2bs(p);
            }
        #pragma unroll
        for (int d = 1; d < 16; d <<= 1)
            #pragma unroll
            for (int i = 0; i < 4; ++i)
                psum[i] += __shfl_xor(psum[i], d, 64);
        #pragma unroll
        for (int i = 0; i < 4; ++i)
            l_run[i] = l_run[i] * corr[i] + psum[i];
        #pragma unroll
        for (int dc = 0; dc < 4; ++dc)
            #pragma unroll
            for (int i = 0; i < 4; ++i)
                oA[dc][i] *= corr[i];

        // ---- P -> wave-private LDS (re-fragment for PV's A operand) ----
        #pragma unroll
        for (int c = 0; c < 4; ++c)
            #pragma unroll
            for (int i = 0; i < 4; ++i) {
                int pr = lhi * 4 + i;
                *(ushort*)(Ps + wbase + swz(pr, (c * 16 + l15) * 2)) = pb[c][i];
            }
        __syncthreads();   // drain LDS writes (cross-lane P visibility)

        // ---- PV: O[16 q][64 d] += P[16][64] x V[64][64] ----
        #pragma unroll
        for (int kc = 0; kc < 2; ++kc) {
            short8 pa = *(const short8*)(Ps + wbase + swz(l15, kc * 64 + lhi * 16));
            #pragma unroll
            for (int dc = 0; dc < 4; ++dc) {
                short8 vb = *(const short8*)(Vt + swz(dc * 16 + l15, kc * 64 + lhi * 16));
                oA[dc] = __builtin_amdgcn_mfma_f32_16x16x32_bf16(pa, vb, oA[dc], 0, 0, 0);
            }
        }
    }

    // ---- epilogue: divide by l, store fp32 ----
    #pragma unroll
    for (int i = 0; i < 4; ++i) {
        float inv = 1.0f / l_run[i];
        size_t orow = ((size_t)b * S + qb + w * 16 + lhi * 4 + i) * D_MODEL + h * DHEAD;
        #pragma unroll
        for (int dc = 0; dc < 4; ++dc)
            O[orow + dc * 16 + l15] = oA[dc][i] * inv;
    }
}

// ---------------------------------------------------------------------------
// y = LayerNorm(x + r), unbiased std (N-1), /(std+eps) per reference.
// ---------------------------------------------------------------------------
__global__ __launch_bounds__(256) void add_ln(
    const float* __restrict__ x, const float* __restrict__ rr,
    const float* __restrict__ gam, const float* __restrict__ bet,
    float* __restrict__ y)
{
    const int row = blockIdx.x;
    const int tid = threadIdx.x;
    const size_t off = (size_t)row * D_MODEL;

    float4 xv = ((const float4*)(x + off))[tid];
    float4 rv = ((const float4*)(rr + off))[tid];
    float v0 = xv.x + rv.x, v1 = xv.y + rv.y, v2 = xv.z + rv.z, v3 = xv.w + rv.w;

    float s  = v0 + v1 + v2 + v3;
    float ss = v0 * v0 + v1 * v1 + v2 * v2 + v3 * v3;

    __shared__ float sb[8];
    #pragma unroll
    for (int o = 32; o > 0; o >>= 1) {
        s  += __shfl_down(s, o, 64);
        ss += __shfl_down(ss, o, 64);
    }
    const int lane = tid & 63, w = tid >> 6;
    if (lane == 0) { sb[w] = s; sb[4 + w] = ss; }
    __syncthreads();
    float S  = sb[0] + sb[1] + sb[2] + sb[3];
    float SS = sb[4] + sb[5] + sb[6] + sb[7];

    float mean = S * (1.f / D_MODEL);
    float var_sum = SS - S * mean;
    float stdv = sqrtf(var_sum * (1.f / (D_MODEL - 1)));
    float inv = 1.f / (stdv + 1e-6f);

    float4 gv = ((const float4*)gam)[tid];
    float4 bv = ((const float4*)bet)[tid];
    float4 out;
    out.x = gv.x * (v0 - mean) * inv + bv.x;
    out.y = gv.y * (v1 - mean) * inv + bv.y;
    out.z = gv.z * (v2 - mean) * inv + bv.z;
    out.w = gv.w * (v3 - mean) * inv + bv.w;
    ((float4*)(y + off))[tid] = out;
}

// ---------------------------------------------------------------------------
extern "C" void kernel_launch(void* const* d_in, const int* in_sizes, int n_in,
                              void* d_out, int out_size, void* d_ws, size_t ws_size,
                              hipStream_t stream)
{
    const float* x     = (const float*)d_in[0];
    const float* enc   = (const float*)d_in[1];
    const float* sa_wq = (const float*)d_in[2];
    const float* sa_wk = (const float*)d_in[3];
    const float* sa_wv = (const float*)d_in[4];
    const float* sa_wo = (const float*)d_in[5];
    const float* ca_wq = (const float*)d_in[6];
    const float* ca_wk = (const float*)d_in[7];
    const float* ca_wv = (const float*)d_in[8];
    const float* ca_wo = (const float*)d_in[9];
    const float* ff_w1 = (const float*)d_in[10];
    const float* ff_b1 = (const float*)d_in[11];
    const float* ff_w2 = (const float*)d_in[12];
    const float* ff_b2 = (const float*)d_in[13];
    const float* ln1_g = (const float*)d_in[14];
    const float* ln1_b = (const float*)d_in[15];
    const float* ln2_g = (const float*)d_in[16];
    const float* ln2_b = (const float*)d_in[17];
    const float* ln3_g = (const float*)d_in[18];
    const float* ln3_b = (const float*)d_in[19];
    float* out = (float*)d_out;

    const int Bn = 2, S = 2048, M = Bn * S;
    const size_t SLOT = (size_t)M * D_MODEL;       // 16 MB fp32 each
    float* s0 = (float*)d_ws;
    float* s1 = s0 + SLOT;
    float* s2 = s1 + SLOT;
    float* s3 = s2 + SLOT;
    float* s4 = s3 + SLOT;
    short* kbuf  = (short*)(s4 + SLOT);            // 8 MB bf16 K tiles
    short* vtbuf = kbuf + (size_t)32 * (S / 64) * 4096;  // 8 MB bf16 V^T tiles
    // peak ws: 96 MB

    dim3 blk(256);
    dim3 g_proj(D_MODEL / 64, M / 64);
    dim3 g_ffh(2048 / 64, M / 64);
    dim3 g_attn(S / 64, Bn * NHEADS);
    dim3 g_prep(S / 64, Bn * NHEADS);
    dim3 g_ln(M);

    // ---- self-attention (causal) ----
    gemm_bt<false,false,false><<<g_proj, blk, 0, stream>>>(x, D_MODEL, sa_wq, D_MODEL, nullptr, s0, D_MODEL, M, D_MODEL, D_MODEL);
    gemm_bt<false,false,false><<<g_proj, blk, 0, stream>>>(x, D_MODEL, sa_wk, D_MODEL, nullptr, s1, D_MODEL, M, D_MODEL, D_MODEL);
    gemm_bt<false,false,false><<<g_proj, blk, 0, stream>>>(x, D_MODEL, sa_wv, D_MODEL, nullptr, s2, D_MODEL, M, D_MODEL, D_MODEL);
    kv_prep<<<g_prep, blk, 0, stream>>>(s1, s2, kbuf, vtbuf, S);
    attn_mfma<true><<<g_attn, blk, 0, stream>>>(s0, kbuf, vtbuf, s3, S);
    gemm_bt<false,false,false><<<g_proj, blk, 0, stream>>>(s3, D_MODEL, sa_wo, D_MODEL, nullptr, s4, D_MODEL, M, D_MODEL, D_MODEL);
    add_ln<<<g_ln, blk, 0, stream>>>(x, s4, ln1_g, ln1_b, s1);   // h1 -> s1

    // ---- cross-attention ----
    gemm_bt<false,false,false><<<g_proj, blk, 0, stream>>>(s1, D_MODEL, ca_wq, D_MODEL, nullptr, s0, D_MODEL, M, D_MODEL, D_MODEL);
    gemm_bt<false,false,false><<<g_proj, blk, 0, stream>>>(enc, D_MODEL, ca_wk, D_MODEL, nullptr, s2, D_MODEL, M, D_MODEL, D_MODEL);
    gemm_bt<false,false,false><<<g_proj, blk, 0, stream>>>(enc, D_MODEL, ca_wv, D_MODEL, nullptr, s3, D_MODEL, M, D_MODEL, D_MODEL);
    kv_prep<<<g_prep, blk, 0, stream>>>(s2, s3, kbuf, vtbuf, S);
    attn_mfma<false><<<g_attn, blk, 0, stream>>>(s0, kbuf, vtbuf, s4, S);
    gemm_bt<false,false,false><<<g_proj, blk, 0, stream>>>(s4, D_MODEL, ca_wo, D_MODEL, nullptr, s0, D_MODEL, M, D_MODEL, D_MODEL);
    add_ln<<<g_ln, blk, 0, stream>>>(s1, s0, ln2_g, ln2_b, s2);  // h2 -> s2

    // ---- FFN, K-split into halves ----
    gemm_bt<true,true,false><<<g_ffh, blk, 0, stream>>>(s2, D_MODEL, ff_w1, D_MODEL, ff_b1, s3, 2048, M, 2048, D_MODEL);
    gemm_bt<false,false,false><<<g_proj, blk, 0, stream>>>(s3, 2048, ff_w2, D_HID, nullptr, s0, D_MODEL, M, D_MODEL, 2048);
    gemm_bt<true,true,false><<<g_ffh, blk, 0, stream>>>(s2, D_MODEL, ff_w1 + (size_t)2048 * D_MODEL, D_MODEL, ff_b1 + 2048, s3, 2048, M, 2048, D_MODEL);
    gemm_bt<true,false,true><<<g_proj, blk, 0, stream>>>(s3, 2048, ff_w2 + 2048, D_HID, ff_b2, s0, D_MODEL, M, D_MODEL, 2048);

    add_ln<<<g_ln, blk, 0, stream>>>(s2, s0, ln3_g, ln3_b, out); // final -> d_out
}

// Round 3
// 615.625 us; speedup vs baseline: 7.4765x; 3.5850x over previous
//
#include <hip/hip_runtime.h>
#include <hip/hip_bf16.h>
#include <math.h>

#define D_MODEL 1024
#define NHEADS  16
#define DHEAD   64
#define D_HID   4096

typedef __attribute__((ext_vector_type(8))) short short8;   // 8 bf16 = 4 VGPR
typedef __attribute__((ext_vector_type(4))) short short4v;
typedef __attribute__((ext_vector_type(4))) float f32x4;

__device__ inline short f2bs(float x) {
    union { __hip_bfloat16 b; short s; } u;
    u.b = __float2bfloat16(x);
    return u.s;
}
__device__ inline float bs2f(ushort s) {
    union { unsigned u; float f; } v; v.u = ((unsigned)s) << 16; return v.f;
}
__device__ inline short8 pack8(float4 x, float4 y) {
    short8 v;
    v[0] = f2bs(x.x); v[1] = f2bs(x.y); v[2] = f2bs(x.z); v[3] = f2bs(x.w);
    v[4] = f2bs(y.x); v[5] = f2bs(y.y); v[6] = f2bs(y.z); v[7] = f2bs(y.w);
    return v;
}
// async global->LDS, 16B per lane; dest = wave-uniform base + lane*16
typedef const unsigned __attribute__((address_space(1))) gu32;
typedef unsigned __attribute__((address_space(3))) lu32;
__device__ inline void gload16(const void* g, void* l) {
    __builtin_amdgcn_global_load_lds((gu32*)g, (lu32*)l, 16, 0, 0);
}
// attention LDS swizzle (round-2 verified)
__device__ inline int swz(int r, int byteInRow) {
    return (r * 128 + byteInRow) ^ ((r & 7) << 4);
}

// ---------------------------------------------------------------------------
// Weight cast/pack: 10 fp32 weights -> one bf16 arena (16M elems).
// Layout (1M-elem units): 0 sa_wq | 1 sa_wk | 2 sa_wv | 3 sa_wo | 4 ca_wq |
// 5 ca_wk | 6 ca_wv | 7 ca_wo | 8..11 ff_w1 | 12..15 ff_w2
// ---------------------------------------------------------------------------
struct WP { const float* p[10]; };
__global__ __launch_bounds__(256) void cast_weights(WP wp, short* __restrict__ dst) {
    const int n8 = (16 << 20) / 8;
    for (int i = blockIdx.x * 256 + threadIdx.x; i < n8; i += gridDim.x * 256) {
        size_t e = (size_t)i * 8;
        int seg = (int)(e >> 20);
        const float* src;
        if (seg < 8)       src = wp.p[seg] + (e & ((1u << 20) - 1));
        else if (seg < 12) src = wp.p[8] + (e - ((size_t)8 << 20));
        else               src = wp.p[9] + (e - ((size_t)12 << 20));
        float4 a = *(const float4*)src;
        float4 b = *(const float4*)(src + 4);
        *(short8*)(dst + e) = pack8(a, b);
    }
}

__global__ __launch_bounds__(256) void cast_f2b(const float* __restrict__ in,
                                                short* __restrict__ out, int n8) {
    for (int i = blockIdx.x * 256 + threadIdx.x; i < n8; i += gridDim.x * 256) {
        float4 a = *(const float4*)(in + (size_t)i * 8);
        float4 b = *(const float4*)(in + (size_t)i * 8 + 4);
        *(short8*)(out + (size_t)i * 8) = pack8(a, b);
    }
}

// ---------------------------------------------------------------------------
// bf16 MFMA GEMM (m97 structure): C[M,N] = A[M,K] * B[N,K]^T
// 128x128 tile, BK=32, 4 waves (2x2), 16x16x32 MFMA, global_load_lds staging.
// OM: 0 = fp32 out (Cf), 1 = bf16 out (Cb, ldc), 2 = bf16 routed out
//     (Cb + (col>>10)*routeElems + row*1024 + (col&1023))  [QKV split]
// ---------------------------------------------------------------------------
template<int OM, bool BIAS, bool RELU, bool ACCUM>
__global__ __launch_bounds__(256) void gemm_mfma(
    const short* __restrict__ A, int lda,
    const short* __restrict__ Bm, int ldb,
    const float* __restrict__ bias,
    float* __restrict__ Cf, short* __restrict__ Cb, int ldc,
    int M, int N, int K, size_t routeElems)
{
    __shared__ short Als[128 * 32];
    __shared__ short Bls[128 * 32];

    const int tid = threadIdx.x, w = tid >> 6, l = tid & 63;
    const int l15 = l & 15, lhi = l >> 4;
    const int wr = w >> 1, wc = w & 1;
    const int bm = blockIdx.y * 128, bn = blockIdx.x * 128;

    // staging coords: issue i covers rows i*64 + w*16 + (l>>2), 16B chunk (l&3)
    const int srow = w * 16 + (l >> 2);
    const int sq   = (l & 3) * 8;          // bf16 elems

    f32x4 acc[4][4] = {};

    for (int k0 = 0; k0 < K; k0 += 32) {
        #pragma unroll
        for (int i = 0; i < 2; ++i) {
            const short* ga = A  + (size_t)(bm + i * 64 + srow) * lda + k0 + sq;
            const short* gb = Bm + (size_t)(bn + i * 64 + srow) * ldb + k0 + sq;
            gload16(ga, &Als[i * 2048 + w * 512]);
            gload16(gb, &Bls[i * 2048 + w * 512]);
        }
        __syncthreads();   // vmcnt(0) drain + barrier

        short8 af[4], bf[4];
        #pragma unroll
        for (int m = 0; m < 4; ++m)
            af[m] = *(const short8*)&Als[(wr * 64 + m * 16 + l15) * 32 + lhi * 8];
        #pragma unroll
        for (int n = 0; n < 4; ++n)
            bf[n] = *(const short8*)&Bls[(wc * 64 + n * 16 + l15) * 32 + lhi * 8];
        #pragma unroll
        for (int m = 0; m < 4; ++m)
            #pragma unroll
            for (int n = 0; n < 4; ++n)
                acc[m][n] = __builtin_amdgcn_mfma_f32_16x16x32_bf16(af[m], bf[n], acc[m][n], 0, 0, 0);
        __syncthreads();   // LDS reads done before next overwrite
    }

    #pragma unroll
    for (int n = 0; n < 4; ++n) {
        const int col = bn + wc * 64 + n * 16 + l15;
        float bv = 0.f;
        if (BIAS) bv = bias[col];
        #pragma unroll
        for (int m = 0; m < 4; ++m) {
            const int row0 = bm + wr * 64 + m * 16 + lhi * 4;
            #pragma unroll
            for (int i = 0; i < 4; ++i) {
                float v = acc[m][n][i] + (BIAS ? bv : 0.f);
                if (ACCUM) v += Cf[(size_t)(row0 + i) * ldc + col];
                if (RELU)  v = fmaxf(v, 0.f);
                if (OM == 0) {
                    Cf[(size_t)(row0 + i) * ldc + col] = v;
                } else if (OM == 1) {
                    Cb[(size_t)(row0 + i) * ldc + col] = f2bs(v);
                } else {
                    Cb[(size_t)(col >> 10) * routeElems +
                       (size_t)(row0 + i) * 1024 + (col & 1023)] = f2bs(v);
                }
            }
        }
    }
}

// ---------------------------------------------------------------------------
// kv_prep (bf16 in): tile K rows and transpose V per (tile, head).
// ---------------------------------------------------------------------------
__global__ __launch_bounds__(256) void kv_prep(
    const short* __restrict__ Kb_, const short* __restrict__ Vb_,
    short* __restrict__ Kt, short* __restrict__ Vt, int S)
{
    const int t = blockIdx.x, bh = blockIdx.y;
    const int b = bh >> 4, h = bh & 15;
    const int tid = threadIdx.x;
    const int r = tid >> 2, g = tid & 3;
    __shared__ ushort vs[64][65];

    const size_t inrow = ((size_t)b * S + t * 64 + r) * D_MODEL + h * DHEAD;
    const size_t tbase = ((size_t)bh * (S / 64) + t) * 4096;

    // K: direct copy into tile
    *(short8*)(Kt + tbase + r * 64 + g * 8)      = *(const short8*)(Kb_ + inrow + g * 8);
    *(short8*)(Kt + tbase + r * 64 + 32 + g * 8) = *(const short8*)(Kb_ + inrow + 32 + g * 8);

    // V: transpose via LDS
    short8 v0 = *(const short8*)(Vb_ + inrow + g * 16);
    short8 v1 = *(const short8*)(Vb_ + inrow + g * 16 + 8);
    #pragma unroll
    for (int j = 0; j < 8; ++j) { vs[r][g * 16 + j] = (ushort)v0[j]; vs[r][g * 16 + 8 + j] = (ushort)v1[j]; }
    __syncthreads();
    short8 q0, q1;
    #pragma unroll
    for (int j = 0; j < 8; ++j) {
        q0[j] = (short)vs[g * 16 + j][r];
        q1[j] = (short)vs[g * 16 + 8 + j][r];
    }
    *(short8*)(Vt + tbase + r * 64 + g * 16)     = q0;
    *(short8*)(Vt + tbase + r * 64 + g * 16 + 8) = q1;
}

// ---------------------------------------------------------------------------
// MFMA flash attention (bf16 Q in, bf16 out). 64 q-rows/block, 4 waves.
// mask BEFORE /32 scale; online softmax rows at (lhi, reg i).
// ---------------------------------------------------------------------------
template<bool CAUSAL>
__global__ __launch_bounds__(256) void attn_mfma(
    const short* __restrict__ Qb, const short* __restrict__ Kt,
    const short* __restrict__ Vt, short* __restrict__ O, int S)
{
    __shared__ __align__(16) char Ks[8192];
    __shared__ __align__(16) char Vs[8192];
    __shared__ __align__(16) char Ps[8192];

    const int tid = threadIdx.x, w = tid >> 6, l = tid & 63;
    const int l15 = l & 15, lhi = l >> 4;
    const int qt = blockIdx.x, bh = blockIdx.y;
    const int b = bh >> 4, h = bh & 15;
    const int qb = qt * 64;

    short8 aq[2];
    {
        const short* qp = Qb + ((size_t)b * S + qb + w * 16 + l15) * D_MODEL + h * DHEAD;
        aq[0] = *(const short8*)(qp + lhi * 8);
        aq[1] = *(const short8*)(qp + 32 + lhi * 8);
    }

    f32x4 oA[4] = {};
    float m_run[4] = {-3.0e38f, -3.0e38f, -3.0e38f, -3.0e38f};
    float l_run[4] = {0.f, 0.f, 0.f, 0.f};

    const int nkt = CAUSAL ? (qt + 1) : (S / 64);
    const size_t hKbase = (size_t)bh * ((S / 64) * 4096);
    const int sr = tid >> 2, sg = tid & 3;
    const int wbase = w * 2048;

    for (int kt = 0; kt < nkt; ++kt) {
        __syncthreads();
        {
            const short* kg = Kt + hKbase + (size_t)kt * 4096;
            const short* vg = Vt + hKbase + (size_t)kt * 4096;
            short8 k0 = *(const short8*)(kg + sr * 64 + sg * 8);
            short8 k1 = *(const short8*)(kg + sr * 64 + 32 + sg * 8);
            short8 v0 = *(const short8*)(vg + sr * 64 + sg * 8);
            short8 v1 = *(const short8*)(vg + sr * 64 + 32 + sg * 8);
            *(short8*)(Ks + swz(sr, sg * 16))      = k0;
            *(short8*)(Ks + swz(sr, 64 + sg * 16)) = k1;
            *(short8*)(Vs + swz(sr, sg * 16))      = v0;
            *(short8*)(Vs + swz(sr, 64 + sg * 16)) = v1;
        }
        __syncthreads();

        f32x4 sA[4] = {};
        #pragma unroll
        for (int kd = 0; kd < 2; ++kd) {
            #pragma unroll
            for (int c = 0; c < 4; ++c) {
                short8 bfr = *(const short8*)(Ks + swz(c * 16 + l15, kd * 64 + lhi * 16));
                sA[c] = __builtin_amdgcn_mfma_f32_16x16x32_bf16(aq[kd], bfr, sA[c], 0, 0, 0);
            }
        }

        float sv[4][4];
        #pragma unroll
        for (int c = 0; c < 4; ++c) {
            #pragma unroll
            for (int i = 0; i < 4; ++i) {
                float s = sA[c][i];
                if (CAUSAL) {
                    int col  = kt * 64 + c * 16 + l15;
                    int qrow = qb + w * 16 + lhi * 4 + i;
                    if (col > qrow) s -= 1.0e10f;
                }
                sv[c][i] = s * 0.03125f;
            }
        }

        float rmax[4];
        #pragma unroll
        for (int i = 0; i < 4; ++i)
            rmax[i] = fmaxf(fmaxf(sv[0][i], sv[1][i]), fmaxf(sv[2][i], sv[3][i]));
        #pragma unroll
        for (int d = 1; d < 16; d <<= 1)
            #pragma unroll
            for (int i = 0; i < 4; ++i)
                rmax[i] = fmaxf(rmax[i], __shfl_xor(rmax[i], d, 64));

        float corr[4], psum[4];
        #pragma unroll
        for (int i = 0; i < 4; ++i) {
            float mn = fmaxf(m_run[i], rmax[i]);
            corr[i]  = __expf(m_run[i] - mn);
            m_run[i] = mn;
            psum[i]  = 0.f;
        }
        ushort pb[4][4];
        #pragma unroll
        for (int c = 0; c < 4; ++c)
            #pragma unroll
            for (int i = 0; i < 4; ++i) {
                float p = __expf(sv[c][i] - m_run[i]);
                psum[i] += p;
                pb[c][i] = (ushort)f2bs(p);
            }
        #pragma unroll
        for (int d = 1; d < 16; d <<= 1)
            #pragma unroll
            for (int i = 0; i < 4; ++i)
                psum[i] += __shfl_xor(psum[i], d, 64);
        #pragma unroll
        for (int i = 0; i < 4; ++i)
            l_run[i] = l_run[i] * corr[i] + psum[i];
        #pragma unroll
        for (int dc = 0; dc < 4; ++dc)
            #pragma unroll
            for (int i = 0; i < 4; ++i)
                oA[dc][i] *= corr[i];

        #pragma unroll
        for (int c = 0; c < 4; ++c)
            #pragma unroll
            for (int i = 0; i < 4; ++i)
                *(ushort*)(Ps + wbase + swz(lhi * 4 + i, (c * 16 + l15) * 2)) = pb[c][i];
        __syncthreads();

        #pragma unroll
        for (int kc = 0; kc < 2; ++kc) {
            short8 pa = *(const short8*)(Ps + wbase + swz(l15, kc * 64 + lhi * 16));
            #pragma unroll
            for (int dc = 0; dc < 4; ++dc) {
                short8 vb = *(const short8*)(Vs + swz(dc * 16 + l15, kc * 64 + lhi * 16));
                oA[dc] = __builtin_amdgcn_mfma_f32_16x16x32_bf16(pa, vb, oA[dc], 0, 0, 0);
            }
        }
    }

    #pragma unroll
    for (int i = 0; i < 4; ++i) {
        float inv = 1.0f / l_run[i];
        short* orow = O + ((size_t)b * S + qb + w * 16 + lhi * 4 + i) * D_MODEL + h * DHEAD;
        #pragma unroll
        for (int dc = 0; dc < 4; ++dc)
            orow[dc * 16 + l15] = f2bs(oA[dc][i] * inv);
    }
}

// ---------------------------------------------------------------------------
// y = LayerNorm(in1 + in2), unbiased (N-1) std, /(std+eps).
// IN1BF: in1 is bf16; OUTBF: emit bf16, else fp32.
// ---------------------------------------------------------------------------
template<bool IN1BF, bool OUTBF>
__global__ __launch_bounds__(256) void add_ln(
    const void* __restrict__ in1, const float* __restrict__ in2,
    const float* __restrict__ gam, const float* __restrict__ bet,
    void* __restrict__ y)
{
    const int row = blockIdx.x;
    const int tid = threadIdx.x;
    const size_t off = (size_t)row * D_MODEL;

    float a0, a1, a2, a3;
    if (IN1BF) {
        short4v xs = ((const short4v*)((const short*)in1 + off))[tid];
        a0 = bs2f((ushort)xs[0]); a1 = bs2f((ushort)xs[1]);
        a2 = bs2f((ushort)xs[2]); a3 = bs2f((ushort)xs[3]);
    } else {
        float4 xv = ((const float4*)((const float*)in1 + off))[tid];
        a0 = xv.x; a1 = xv.y; a2 = xv.z; a3 = xv.w;
    }
    float4 rv = ((const float4*)(in2 + off))[tid];
    float v0 = a0 + rv.x, v1 = a1 + rv.y, v2 = a2 + rv.z, v3 = a3 + rv.w;

    float s  = v0 + v1 + v2 + v3;
    float ss = v0 * v0 + v1 * v1 + v2 * v2 + v3 * v3;

    __shared__ float sb[8];
    #pragma unroll
    for (int o = 32; o > 0; o >>= 1) {
        s  += __shfl_down(s, o, 64);
        ss += __shfl_down(ss, o, 64);
    }
    const int lane = tid & 63, w = tid >> 6;
    if (lane == 0) { sb[w] = s; sb[4 + w] = ss; }
    __syncthreads();
    float S  = sb[0] + sb[1] + sb[2] + sb[3];
    float SS = sb[4] + sb[5] + sb[6] + sb[7];

    float mean = S * (1.f / D_MODEL);
    float var_sum = SS - S * mean;
    float stdv = sqrtf(var_sum * (1.f / (D_MODEL - 1)));
    float inv = 1.f / (stdv + 1e-6f);

    float4 gv = ((const float4*)gam)[tid];
    float4 bv = ((const float4*)bet)[tid];
    float o0 = gv.x * (v0 - mean) * inv + bv.x;
    float o1 = gv.y * (v1 - mean) * inv + bv.y;
    float o2 = gv.z * (v2 - mean) * inv + bv.z;
    float o3 = gv.w * (v3 - mean) * inv + bv.w;
    if (OUTBF) {
        short4v ov; ov[0] = f2bs(o0); ov[1] = f2bs(o1); ov[2] = f2bs(o2); ov[3] = f2bs(o3);
        ((short4v*)((short*)y + off))[tid] = ov;
    } else {
        ((float4*)((float*)y + off))[tid] = make_float4(o0, o1, o2, o3);
    }
}

// ---------------------------------------------------------------------------
extern "C" void kernel_launch(void* const* d_in, const int* in_sizes, int n_in,
                              void* d_out, int out_size, void* d_ws, size_t ws_size,
                              hipStream_t stream)
{
    const float* x     = (const float*)d_in[0];
    const float* enc   = (const float*)d_in[1];
    WP wp;
    for (int i = 0; i < 8; ++i) wp.p[i] = (const float*)d_in[2 + i];  // sa_wq..ca_wo
    wp.p[8] = (const float*)d_in[10];   // ff_w1
    wp.p[9] = (const float*)d_in[12];   // ff_w2
    const float* ff_b1 = (const float*)d_in[11];
    const float* ff_b2 = (const float*)d_in[13];
    const float* ln1_g = (const float*)d_in[14];
    const float* ln1_b = (const float*)d_in[15];
    const float* ln2_g = (const float*)d_in[16];
    const float* ln2_b = (const float*)d_in[17];
    const float* ln3_g = (const float*)d_in[18];
    const float* ln3_b = (const float*)d_in[19];
    float* out = (float*)d_out;

    const int Bn = 2, S = 2048, M = Bn * S;     // 4096 rows
    const size_t MB = 1u << 20;
    char* ws = (char*)d_ws;
    // byte-offset layout (96 MB total, liveness-aliased):
    short* Wb   = (short*)(ws);                 // [0,32MB) bf16 weights arena
    short* p32  = (short*)(ws + 32 * MB);       // xb / attnOut / h1b
    short* p40  = (short*)(ws + 40 * MB);       // Qb / h2b
    short* p48  = (short*)(ws + 48 * MB);       // Kraw / attnOutB
    short* p56  = (short*)(ws + 56 * MB);       // Vraw ; FFN t-half [56,72)
    short* p64  = (short*)(ws + 64 * MB);       // Ktiles / encb
    short* p72  = (short*)(ws + 72 * MB);       // Vtiles
    float* f0   = (float*)(ws + 80 * MB);       // fp32 scratch [80,96)

    const size_t RT = 4 * MB;                   // route stride: 4M bf16 elems
    const short* W_saqkv = Wb;                  // [3072][1024]
    const short* W_sawo  = Wb + 3 * MB;
    const short* W_caq   = Wb + 4 * MB;
    const short* W_cakv  = Wb + 5 * MB;         // [2048][1024]
    const short* W_cawo  = Wb + 7 * MB;
    const short* W_ff1   = Wb + 8 * MB;         // [4096][1024]
    const short* W_ff2   = Wb + 12 * MB;        // [1024][4096]

    dim3 blk(256);
    dim3 g_qkv(3072 / 128, M / 128);
    dim3 g_kv(2048 / 128, M / 128);
    dim3 g_n1k(1024 / 128, M / 128);
    dim3 g_ffh(2048 / 128, M / 128);
    dim3 g_attn(S / 64, Bn * NHEADS);
    dim3 g_ln(M);

    // ---- casts ----
    cast_weights<<<2048, blk, 0, stream>>>(wp, Wb);
    cast_f2b<<<2048, blk, 0, stream>>>(x, p32, (M * D_MODEL) / 8);        // xb

    // ---- self-attention (causal) ----
    gemm_mfma<2,false,false,false><<<g_qkv, blk, 0, stream>>>(p32, 1024, W_saqkv, 1024, nullptr, nullptr, p40, 1024, M, 3072, 1024, RT);  // Q->p40,K->p48,V->p56
    kv_prep<<<dim3(S/64, Bn*NHEADS), blk, 0, stream>>>(p48, p56, p64, p72, S);
    attn_mfma<true><<<g_attn, blk, 0, stream>>>(p40, p64, p72, p32, S);   // attnOut->p32 (xb dead)
    gemm_mfma<0,false,false,false><<<g_n1k, blk, 0, stream>>>(p32, 1024, W_sawo, 1024, nullptr, f0, nullptr, 1024, M, 1024, 1024, 0);
    add_ln<false,true><<<g_ln, blk, 0, stream>>>(x, f0, ln1_g, ln1_b, p32);   // h1b -> p32

    // ---- cross-attention ----
    cast_f2b<<<2048, blk, 0, stream>>>(enc, p64, (M * D_MODEL) / 8);      // encb -> p64 (Ktiles dead)
    gemm_mfma<2,false,false,false><<<g_kv, blk, 0, stream>>>(p64, 1024, W_cakv, 1024, nullptr, nullptr, p48, 1024, M, 2048, 1024, RT);    // K->p48,V->p56
    gemm_mfma<1,false,false,false><<<g_n1k, blk, 0, stream>>>(p32, 1024, W_caq, 1024, nullptr, nullptr, p40, 1024, M, 1024, 1024, 0);     // Q->p40
    kv_prep<<<dim3(S/64, Bn*NHEADS), blk, 0, stream>>>(p48, p56, p64, p72, S);  // encb dead -> Ktiles
    attn_mfma<false><<<g_attn, blk, 0, stream>>>(p40, p64, p72, p48, S);  // attnOut->p48 (Kraw dead)
    gemm_mfma<0,false,false,false><<<g_n1k, blk, 0, stream>>>(p48, 1024, W_cawo, 1024, nullptr, f0, nullptr, 1024, M, 1024, 1024, 0);
    add_ln<true,true><<<g_ln, blk, 0, stream>>>(p32, f0, ln2_g, ln2_b, p40);  // h2b -> p40 (Qb dead)

    // ---- FFN, K-split halves; t-half bf16 at p56 [56,72) ----
    gemm_mfma<1,true,true,false><<<g_ffh, blk, 0, stream>>>(p40, 1024, W_ff1, 1024, ff_b1, nullptr, p56, 2048, M, 2048, 1024, 0);
    gemm_mfma<0,false,false,false><<<g_n1k, blk, 0, stream>>>(p56, 2048, W_ff2, 4096, nullptr, f0, nullptr, 1024, M, 1024, 2048, 0);
    gemm_mfma<1,true,true,false><<<g_ffh, blk, 0, stream>>>(p40, 1024, W_ff1 + (size_t)2048 * 1024, 1024, ff_b1 + 2048, nullptr, p56, 2048, M, 2048, 1024, 0);
    gemm_mfma<0,true,false,true><<<g_n1k, blk, 0, stream>>>(p56, 2048, W_ff2 + 2048, 4096, ff_b2, f0, nullptr, 1024, M, 1024, 2048, 0);

    add_ln<true,false><<<g_ln, blk, 0, stream>>>(p40, f0, ln3_g, ln3_b, out);
}

// Round 4
// 611.650 us; speedup vs baseline: 7.5251x; 1.0065x over previous
//
#include <hip/hip_runtime.h>
#include <hip/hip_bf16.h>
#include <math.h>

#define D_MODEL 1024
#define NHEADS  16
#define DHEAD   64
#define D_HID   4096

typedef __attribute__((ext_vector_type(8))) short short8;   // 8 bf16 = 4 VGPR
typedef __attribute__((ext_vector_type(4))) short short4v;
typedef __attribute__((ext_vector_type(4))) float f32x4;
typedef __attribute__((ext_vector_type(16))) float f32x16;  // 32x32 mfma acc

__device__ inline short f2bs(float x) {
    union { __hip_bfloat16 b; short s; } u;
    u.b = __float2bfloat16(x);
    return u.s;
}
__device__ inline float bs2f(ushort s) {
    union { unsigned u; float f; } v; v.u = ((unsigned)s) << 16; return v.f;
}
__device__ inline short8 pack8(float4 x, float4 y) {
    short8 v;
    v[0] = f2bs(x.x); v[1] = f2bs(x.y); v[2] = f2bs(x.z); v[3] = f2bs(x.w);
    v[4] = f2bs(y.x); v[5] = f2bs(y.y); v[6] = f2bs(y.z); v[7] = f2bs(y.w);
    return v;
}
// async global->LDS, 16B per lane; dest = wave-uniform base + lane*16
typedef const unsigned __attribute__((address_space(1))) gu32;
typedef unsigned __attribute__((address_space(3))) lu32;
__device__ inline void gload16(const void* g, void* l) {
    __builtin_amdgcn_global_load_lds((gu32*)g, (lu32*)l, 16, 0, 0);
}

// ---------------------------------------------------------------------------
// Weight cast/pack: 10 fp32 weights -> one bf16 arena (16M elems).
// ---------------------------------------------------------------------------
struct WP { const float* p[10]; };
__global__ __launch_bounds__(256) void cast_weights(WP wp, short* __restrict__ dst) {
    const int n8 = (16 << 20) / 8;
    for (int i = blockIdx.x * 256 + threadIdx.x; i < n8; i += gridDim.x * 256) {
        size_t e = (size_t)i * 8;
        int seg = (int)(e >> 20);
        const float* src;
        if (seg < 8)       src = wp.p[seg] + (e & ((1u << 20) - 1));
        else if (seg < 12) src = wp.p[8] + (e - ((size_t)8 << 20));
        else               src = wp.p[9] + (e - ((size_t)12 << 20));
        float4 a = *(const float4*)src;
        float4 b = *(const float4*)(src + 4);
        *(short8*)(dst + e) = pack8(a, b);
    }
}

__global__ __launch_bounds__(256) void cast_f2b(const float* __restrict__ in,
                                                short* __restrict__ out, int n8) {
    for (int i = blockIdx.x * 256 + threadIdx.x; i < n8; i += gridDim.x * 256) {
        float4 a = *(const float4*)(in + (size_t)i * 8);
        float4 b = *(const float4*)(in + (size_t)i * 8 + 4);
        *(short8*)(out + (size_t)i * 8) = pack8(a, b);
    }
}

// ---------------------------------------------------------------------------
// bf16 MFMA GEMM (m97 structure): C[M,N] = A[M,K] * B[N,K]^T
// OM: 0 = fp32 out, 1 = bf16 out, 2 = bf16 routed (QKV split)
// ---------------------------------------------------------------------------
template<int OM, bool BIAS, bool RELU, bool ACCUM>
__global__ __launch_bounds__(256) void gemm_mfma(
    const short* __restrict__ A, int lda,
    const short* __restrict__ Bm, int ldb,
    const float* __restrict__ bias,
    float* __restrict__ Cf, short* __restrict__ Cb, int ldc,
    int M, int N, int K, size_t routeElems)
{
    __shared__ short Als[128 * 32];
    __shared__ short Bls[128 * 32];

    const int tid = threadIdx.x, w = tid >> 6, l = tid & 63;
    const int l15 = l & 15, lhi = l >> 4;
    const int wr = w >> 1, wc = w & 1;
    const int bm = blockIdx.y * 128, bn = blockIdx.x * 128;

    const int srow = w * 16 + (l >> 2);
    const int sq   = (l & 3) * 8;

    f32x4 acc[4][4] = {};

    for (int k0 = 0; k0 < K; k0 += 32) {
        #pragma unroll
        for (int i = 0; i < 2; ++i) {
            const short* ga = A  + (size_t)(bm + i * 64 + srow) * lda + k0 + sq;
            const short* gb = Bm + (size_t)(bn + i * 64 + srow) * ldb + k0 + sq;
            gload16(ga, &Als[i * 2048 + w * 512]);
            gload16(gb, &Bls[i * 2048 + w * 512]);
        }
        __syncthreads();

        short8 af[4], bf[4];
        #pragma unroll
        for (int m = 0; m < 4; ++m)
            af[m] = *(const short8*)&Als[(wr * 64 + m * 16 + l15) * 32 + lhi * 8];
        #pragma unroll
        for (int n = 0; n < 4; ++n)
            bf[n] = *(const short8*)&Bls[(wc * 64 + n * 16 + l15) * 32 + lhi * 8];
        #pragma unroll
        for (int m = 0; m < 4; ++m)
            #pragma unroll
            for (int n = 0; n < 4; ++n)
                acc[m][n] = __builtin_amdgcn_mfma_f32_16x16x32_bf16(af[m], bf[n], acc[m][n], 0, 0, 0);
        __syncthreads();
    }

    #pragma unroll
    for (int n = 0; n < 4; ++n) {
        const int col = bn + wc * 64 + n * 16 + l15;
        float bv = 0.f;
        if (BIAS) bv = bias[col];
        #pragma unroll
        for (int m = 0; m < 4; ++m) {
            const int row0 = bm + wr * 64 + m * 16 + lhi * 4;
            #pragma unroll
            for (int i = 0; i < 4; ++i) {
                float v = acc[m][n][i] + (BIAS ? bv : 0.f);
                if (ACCUM) v += Cf[(size_t)(row0 + i) * ldc + col];
                if (RELU)  v = fmaxf(v, 0.f);
                if (OM == 0) {
                    Cf[(size_t)(row0 + i) * ldc + col] = v;
                } else if (OM == 1) {
                    Cb[(size_t)(row0 + i) * ldc + col] = f2bs(v);
                } else {
                    Cb[(size_t)(col >> 10) * routeElems +
                       (size_t)(row0 + i) * 1024 + (col & 1023)] = f2bs(v);
                }
            }
        }
    }
}

// ---------------------------------------------------------------------------
// v_prep (bf16 in): transpose V per (tile, head) -> Vt[bh][t][d=64][kv=64]
// ---------------------------------------------------------------------------
__global__ __launch_bounds__(256) void v_prep(
    const short* __restrict__ Vb_, short* __restrict__ Vt, int S)
{
    const int t = blockIdx.x, bh = blockIdx.y;
    const int b = bh >> 4, h = bh & 15;
    const int tid = threadIdx.x;
    const int r = tid >> 2, g = tid & 3;
    __shared__ ushort vs[64][65];

    const size_t inrow = ((size_t)b * S + t * 64 + r) * D_MODEL + h * DHEAD;
    const size_t tbase = ((size_t)bh * (S / 64) + t) * 4096;

    short8 v0 = *(const short8*)(Vb_ + inrow + g * 16);
    short8 v1 = *(const short8*)(Vb_ + inrow + g * 16 + 8);
    #pragma unroll
    for (int j = 0; j < 8; ++j) { vs[r][g * 16 + j] = (ushort)v0[j]; vs[r][g * 16 + 8 + j] = (ushort)v1[j]; }
    __syncthreads();
    short8 q0, q1;
    #pragma unroll
    for (int j = 0; j < 8; ++j) {
        q0[j] = (short)vs[g * 16 + j][r];
        q1[j] = (short)vs[g * 16 + 8 + j][r];
    }
    *(short8*)(Vt + tbase + r * 64 + g * 16)     = q0;
    *(short8*)(Vt + tbase + r * 64 + g * 16 + 8) = q1;
}

// ---------------------------------------------------------------------------
// attn_v2: swapped-operand 32x32 MFMA flash attention. No LDS, no barriers.
// Block = 4 independent waves, each owns 32 q rows. KV step = 32.
// S^T = mfma(A=K, B=Q^T): lane holds S^T[kv][q], q = lane&31,
//   kv = kv0 + (r&3) + 8*(r>>2) + 4*(lane>>5).
// P packed to bf16 in-reg; partner half via shfl_xor(32); PV computes
// O^T[d][q] = mfma(A=V^T, B=P^T). mask BEFORE /32 scale (reference).
// ---------------------------------------------------------------------------
template<bool CAUSAL>
__global__ __launch_bounds__(256) void attn_v2(
    const short* __restrict__ Qb, const short* __restrict__ Kr,
    const short* __restrict__ Vt, short* __restrict__ O, int S)
{
    const int tid = threadIdx.x, w = tid >> 6, l = tid & 63;
    const int l31 = l & 31, hi = l >> 5;
    const int bh = blockIdx.y, b = bh >> 4, h = bh & 15;
    const int qw = blockIdx.x * 128 + w * 32;
    const int q  = qw + l31;

    // Q as B-operand: col=q (lane&31), k = d = dc*16 + hi*8 + j
    const short* qp = Qb + ((size_t)(b * S + q)) * 1024 + h * 64 + hi * 8;
    short8 bq[4];
    #pragma unroll
    for (int dc = 0; dc < 4; ++dc) bq[dc] = *(const short8*)(qp + dc * 16);

    const short* kbase = Kr + ((size_t)b * S) * 1024 + h * 64 + hi * 8;
    const short* vbase = Vt + (size_t)bh * ((S / 64) * 4096);

    f32x16 ot0 = {}, ot1 = {};
    float m_run = -3.0e38f, l_run = 0.f;

    const int ktEnd = CAUSAL ? (qw >> 5) : (S / 32 - 1);
    for (int kt = 0; kt <= ktEnd; ++kt) {
        const int kv0 = kt * 32;

        // ---- QK^T (swapped): A = K rows (row=kv, k=d) ----
        f32x16 st = {};
        const short* krow = kbase + (size_t)(kv0 + l31) * 1024;
        #pragma unroll
        for (int dc = 0; dc < 4; ++dc) {
            short8 ak = *(const short8*)(krow + dc * 16);
            st = __builtin_amdgcn_mfma_f32_32x32x16_bf16(ak, bq[dc], st, 0, 0, 0);
        }

        float sv[16];
        #pragma unroll
        for (int r = 0; r < 16; ++r) sv[r] = st[r];
        if (CAUSAL && kt == ktEnd) {          // diagonal tile only
            #pragma unroll
            for (int r = 0; r < 16; ++r) {
                int kv = kv0 + (r & 3) + 8 * (r >> 2) + 4 * hi;
                if (kv > q) sv[r] -= 1.0e10f;  // mask BEFORE scale
            }
        }
        #pragma unroll
        for (int r = 0; r < 16; ++r) sv[r] *= 0.03125f;  // 1/sqrt(1024)

        // ---- online softmax (per q row; 2 lanes/row) ----
        float pmax = sv[0];
        #pragma unroll
        for (int r = 1; r < 16; ++r) pmax = fmaxf(pmax, sv[r]);
        pmax = fmaxf(pmax, __shfl_xor(pmax, 32, 64));
        float mnew = fmaxf(m_run, pmax);
        float corr = __expf(m_run - mnew);
        m_run = mnew;

        float p[16], psum = 0.f;
        #pragma unroll
        for (int r = 0; r < 16; ++r) { p[r] = __expf(sv[r] - mnew); psum += p[r]; }
        psum += __shfl_xor(psum, 32, 64);
        l_run = l_run * corr + psum;
        #pragma unroll
        for (int r = 0; r < 16; ++r) { ot0[r] *= corr; ot1[r] *= corr; }

        // ---- P -> bf16 words; partner half via shfl_xor(32) ----
        unsigned wd[8], sx[8];
        #pragma unroll
        for (int i = 0; i < 8; ++i)
            wd[i] = (unsigned)(ushort)f2bs(p[2 * i]) |
                    ((unsigned)(ushort)f2bs(p[2 * i + 1]) << 16);
        #pragma unroll
        for (int i = 0; i < 8; ++i) sx[i] = __shfl_xor(wd[i], 32, 64);

        union U { unsigned u[4]; short8 s; };
        U b0, b1;
        if (hi == 0) {
            b0.u[0] = wd[0]; b0.u[1] = wd[1]; b0.u[2] = sx[0]; b0.u[3] = sx[1];
            b1.u[0] = wd[4]; b1.u[1] = wd[5]; b1.u[2] = sx[4]; b1.u[3] = sx[5];
        } else {
            b0.u[0] = sx[2]; b0.u[1] = sx[3]; b0.u[2] = wd[2]; b0.u[3] = wd[3];
            b1.u[0] = sx[6]; b1.u[1] = sx[7]; b1.u[2] = wd[6]; b1.u[3] = wd[7];
        }

        // ---- PV: O^T[d][q] += V^T[d][kv] * P^T[kv][q] ----
        const short* vt = vbase + (size_t)(kv0 >> 6) * 4096 + (kv0 & 32) + hi * 8;
        short8 av;
        av  = *(const short8*)(vt + (size_t)l31 * 64);
        ot0 = __builtin_amdgcn_mfma_f32_32x32x16_bf16(av, b0.s, ot0, 0, 0, 0);
        av  = *(const short8*)(vt + (size_t)l31 * 64 + 16);
        ot0 = __builtin_amdgcn_mfma_f32_32x32x16_bf16(av, b1.s, ot0, 0, 0, 0);
        av  = *(const short8*)(vt + (size_t)(32 + l31) * 64);
        ot1 = __builtin_amdgcn_mfma_f32_32x32x16_bf16(av, b0.s, ot1, 0, 0, 0);
        av  = *(const short8*)(vt + (size_t)(32 + l31) * 64 + 16);
        ot1 = __builtin_amdgcn_mfma_f32_32x32x16_bf16(av, b1.s, ot1, 0, 0, 0);
    }

    // ---- epilogue: lane holds O^T[d][q]; d pairs are consecutive ----
    const float inv = 1.f / l_run;
    short* orow = O + ((size_t)(b * S + q)) * 1024 + h * 64;
    #pragma unroll
    for (int i = 0; i < 8; ++i) {
        int dbase = ((2 * i) & 3) + 8 * (i >> 1) + 4 * hi;
        unsigned u0 = (unsigned)(ushort)f2bs(ot0[2 * i] * inv) |
                      ((unsigned)(ushort)f2bs(ot0[2 * i + 1] * inv) << 16);
        unsigned u1 = (unsigned)(ushort)f2bs(ot1[2 * i] * inv) |
                      ((unsigned)(ushort)f2bs(ot1[2 * i + 1] * inv) << 16);
        *(unsigned*)(orow + dbase)      = u0;
        *(unsigned*)(orow + 32 + dbase) = u1;
    }
}

// ---------------------------------------------------------------------------
// y = LayerNorm(in1 + in2), unbiased (N-1) std, /(std+eps).
// ---------------------------------------------------------------------------
template<bool IN1BF, bool OUTBF>
__global__ __launch_bounds__(256) void add_ln(
    const void* __restrict__ in1, const float* __restrict__ in2,
    const float* __restrict__ gam, const float* __restrict__ bet,
    void* __restrict__ y)
{
    const int row = blockIdx.x;
    const int tid = threadIdx.x;
    const size_t off = (size_t)row * D_MODEL;

    float a0, a1, a2, a3;
    if (IN1BF) {
        short4v xs = ((const short4v*)((const short*)in1 + off))[tid];
        a0 = bs2f((ushort)xs[0]); a1 = bs2f((ushort)xs[1]);
        a2 = bs2f((ushort)xs[2]); a3 = bs2f((ushort)xs[3]);
    } else {
        float4 xv = ((const float4*)((const float*)in1 + off))[tid];
        a0 = xv.x; a1 = xv.y; a2 = xv.z; a3 = xv.w;
    }
    float4 rv = ((const float4*)(in2 + off))[tid];
    float v0 = a0 + rv.x, v1 = a1 + rv.y, v2 = a2 + rv.z, v3 = a3 + rv.w;

    float s  = v0 + v1 + v2 + v3;
    float ss = v0 * v0 + v1 * v1 + v2 * v2 + v3 * v3;

    __shared__ float sb[8];
    #pragma unroll
    for (int o = 32; o > 0; o >>= 1) {
        s  += __shfl_down(s, o, 64);
        ss += __shfl_down(ss, o, 64);
    }
    const int lane = tid & 63, w = tid >> 6;
    if (lane == 0) { sb[w] = s; sb[4 + w] = ss; }
    __syncthreads();
    float S  = sb[0] + sb[1] + sb[2] + sb[3];
    float SS = sb[4] + sb[5] + sb[6] + sb[7];

    float mean = S * (1.f / D_MODEL);
    float var_sum = SS - S * mean;
    float stdv = sqrtf(var_sum * (1.f / (D_MODEL - 1)));
    float inv = 1.f / (stdv + 1e-6f);

    float4 gv = ((const float4*)gam)[tid];
    float4 bv = ((const float4*)bet)[tid];
    float o0 = gv.x * (v0 - mean) * inv + bv.x;
    float o1 = gv.y * (v1 - mean) * inv + bv.y;
    float o2 = gv.z * (v2 - mean) * inv + bv.z;
    float o3 = gv.w * (v3 - mean) * inv + bv.w;
    if (OUTBF) {
        short4v ov; ov[0] = f2bs(o0); ov[1] = f2bs(o1); ov[2] = f2bs(o2); ov[3] = f2bs(o3);
        ((short4v*)((short*)y + off))[tid] = ov;
    } else {
        ((float4*)((float*)y + off))[tid] = make_float4(o0, o1, o2, o3);
    }
}

// ---------------------------------------------------------------------------
extern "C" void kernel_launch(void* const* d_in, const int* in_sizes, int n_in,
                              void* d_out, int out_size, void* d_ws, size_t ws_size,
                              hipStream_t stream)
{
    const float* x     = (const float*)d_in[0];
    const float* enc   = (const float*)d_in[1];
    WP wp;
    for (int i = 0; i < 8; ++i) wp.p[i] = (const float*)d_in[2 + i];
    wp.p[8] = (const float*)d_in[10];   // ff_w1
    wp.p[9] = (const float*)d_in[12];   // ff_w2
    const float* ff_b1 = (const float*)d_in[11];
    const float* ff_b2 = (const float*)d_in[13];
    const float* ln1_g = (const float*)d_in[14];
    const float* ln1_b = (const float*)d_in[15];
    const float* ln2_g = (const float*)d_in[16];
    const float* ln2_b = (const float*)d_in[17];
    const float* ln3_g = (const float*)d_in[18];
    const float* ln3_b = (const float*)d_in[19];
    float* out = (float*)d_out;

    const int Bn = 2, S = 2048, M = Bn * S;
    const size_t MB = 1u << 20;
    char* ws = (char*)d_ws;
    short* Wb   = (short*)(ws);                 // [0,32MB) bf16 weights
    short* p32  = (short*)(ws + 32 * MB);       // xb / saOut / h1b
    short* p40  = (short*)(ws + 40 * MB);       // Qb / h2b
    short* p48  = (short*)(ws + 48 * MB);       // K (raw, read by attn)
    short* p56  = (short*)(ws + 56 * MB);       // V raw / caOut ; FFN t [56,72)
    short* p64  = (short*)(ws + 64 * MB);       // encb
    short* p72  = (short*)(ws + 72 * MB);       // V^T tiles
    float* f0   = (float*)(ws + 80 * MB);       // fp32 scratch [80,96)

    const size_t RT = 4 * MB;
    const short* W_saqkv = Wb;
    const short* W_sawo  = Wb + 3 * MB;
    const short* W_caq   = Wb + 4 * MB;
    const short* W_cakv  = Wb + 5 * MB;
    const short* W_cawo  = Wb + 7 * MB;
    const short* W_ff1   = Wb + 8 * MB;
    const short* W_ff2   = Wb + 12 * MB;

    dim3 blk(256);
    dim3 g_qkv(3072 / 128, M / 128);
    dim3 g_kv(2048 / 128, M / 128);
    dim3 g_n1k(1024 / 128, M / 128);
    dim3 g_ffh(2048 / 128, M / 128);
    dim3 g_attn(S / 128, Bn * NHEADS);
    dim3 g_vp(S / 64, Bn * NHEADS);
    dim3 g_ln(M);

    cast_weights<<<2048, blk, 0, stream>>>(wp, Wb);
    cast_f2b<<<2048, blk, 0, stream>>>(x, p32, (M * D_MODEL) / 8);

    // ---- self-attention (causal) ----
    gemm_mfma<2,false,false,false><<<g_qkv, blk, 0, stream>>>(p32, 1024, W_saqkv, 1024, nullptr, nullptr, p40, 1024, M, 3072, 1024, RT);  // Q->p40 K->p48 V->p56
    v_prep<<<g_vp, blk, 0, stream>>>(p56, p72, S);
    attn_v2<true><<<g_attn, blk, 0, stream>>>(p40, p48, p72, p32, S);     // out->p32 (xb dead)
    gemm_mfma<0,false,false,false><<<g_n1k, blk, 0, stream>>>(p32, 1024, W_sawo, 1024, nullptr, f0, nullptr, 1024, M, 1024, 1024, 0);
    add_ln<false,true><<<g_ln, blk, 0, stream>>>(x, f0, ln1_g, ln1_b, p32);   // h1b

    // ---- cross-attention ----
    cast_f2b<<<2048, blk, 0, stream>>>(enc, p64, (M * D_MODEL) / 8);
    gemm_mfma<2,false,false,false><<<g_kv, blk, 0, stream>>>(p64, 1024, W_cakv, 1024, nullptr, nullptr, p48, 1024, M, 2048, 1024, RT);    // K->p48 V->p56
    gemm_mfma<1,false,false,false><<<g_n1k, blk, 0, stream>>>(p32, 1024, W_caq, 1024, nullptr, nullptr, p40, 1024, M, 1024, 1024, 0);     // Q->p40
    v_prep<<<g_vp, blk, 0, stream>>>(p56, p72, S);
    attn_v2<false><<<g_attn, blk, 0, stream>>>(p40, p48, p72, p56, S);    // out->p56 (Vraw dead)
    gemm_mfma<0,false,false,false><<<g_n1k, blk, 0, stream>>>(p56, 1024, W_cawo, 1024, nullptr, f0, nullptr, 1024, M, 1024, 1024, 0);
    add_ln<true,true><<<g_ln, blk, 0, stream>>>(p32, f0, ln2_g, ln2_b, p40);  // h2b

    // ---- FFN, K-split halves; t-half at p56 [56,72) ----
    gemm_mfma<1,true,true,false><<<g_ffh, blk, 0, stream>>>(p40, 1024, W_ff1, 1024, ff_b1, nullptr, p56, 2048, M, 2048, 1024, 0);
    gemm_mfma<0,false,false,false><<<g_n1k, blk, 0, stream>>>(p56, 2048, W_ff2, 4096, nullptr, f0, nullptr, 1024, M, 1024, 2048, 0);
    gemm_mfma<1,true,true,false><<<g_ffh, blk, 0, stream>>>(p40, 1024, W_ff1 + (size_t)2048 * 1024, 1024, ff_b1 + 2048, nullptr, p56, 2048, M, 2048, 1024, 0);
    gemm_mfma<0,true,false,true><<<g_n1k, blk, 0, stream>>>(p56, 2048, W_ff2 + 2048, 4096, ff_b2, f0, nullptr, 1024, M, 1024, 2048, 0);

    add_ln<true,false><<<g_ln, blk, 0, stream>>>(p40, f0, ln3_g, ln3_b, out);
}